// Round 9
// baseline (1116.616 us; speedup 1.0000x reference)
//
#include <hip/hip_runtime.h>
#include <hip/hip_bf16.h>

#define NFEAT 128
#define BCAP 8192     // max edges per 256-node bucket (csr_build LDS capacity)
#define BSHIFT 8      // 256 nodes per bucket
#define CHUNK 8192    // bin-pass chunk size (edges per count/scatter block)
#define AGG_UNIT 128  // nodes per aggregation work unit

typedef __attribute__((ext_vector_type(8))) short short8;
typedef __attribute__((ext_vector_type(4))) float float4v;
typedef __attribute__((ext_vector_type(2))) unsigned uint2v;

__device__ inline short f32_bf16(float f) {
  unsigned u = __builtin_bit_cast(unsigned, f);
  unsigned r = (u + 0x7fffu + ((u >> 16) & 1u)) >> 16;
  return (short)r;
}
__device__ inline float bf16_f32(unsigned short s) {
  return __builtin_bit_cast(float, (unsigned)s << 16);
}
__device__ inline float bf16_lo(unsigned u) {
  return __builtin_bit_cast(float, u << 16);
}
__device__ inline float bf16_hi(unsigned u) {
  return __builtin_bit_cast(float, u & 0xffff0000u);
}

// Real XCD id of the CU this block runs on. HW_REG_XCC_ID = 20 (gfx940+),
// getreg imm = ((size-1)<<11) | (offset<<6) | id. [measured: learn_hip m09]
// Used only as a locality hint — correctness never depends on it.
__device__ inline int get_xcc() {
  return __builtin_amdgcn_s_getreg(((32 - 1) << 11) | (0 << 6) | 20) & 7;
}

// ---------------------------------------------------------------------------
// Repack W (fp32, KxCOLS row-major) into B-fragment order for
// mfma_f32_16x16x32_bf16.
// ---------------------------------------------------------------------------
__device__ inline void repack_one(const float* __restrict__ W,
                                  short* __restrict__ Wf, int COLS) {
  int nfrag = (COLS / 16) * 4 * 64;
  for (int f = threadIdx.x; f < nfrag; f += 256) {
    int lane = f & 63, c = (f >> 6) & 3, t = f >> 8;
    int k0 = c * 32 + (lane >> 4) * 8;
    int n = t * 16 + (lane & 15);
    short8 v;
#pragma unroll
    for (int j = 0; j < 8; j++) v[j] = f32_bf16(W[(size_t)(k0 + j) * COLS + n]);
    *(short8*)&Wf[(size_t)f * 8] = v;
  }
}
__global__ __launch_bounds__(256) void repack_w_kernel(
    const float* __restrict__ W1, short* __restrict__ W1f,
    const float* __restrict__ W2, short* __restrict__ W2f) {
  if (blockIdx.x == 0) repack_one(W1, W1f, 128);
  else repack_one(W2, W2f, 64);
}

// ---------------------------------------------------------------------------
// GEMM device role: Y = A[nrows x 128] @ W[128 x COLS], output written
// PLANE-MAJOR: Y[t][row][16] for tile t (16-col slices, contiguous 3.2 MB
// planes -> each plane fits one XCD L2 for the sliced aggregation).
// ---------------------------------------------------------------------------
template <int COLS, bool IN_BF16>
__device__ inline void gemm_role(int bid, const void* __restrict__ Av,
                                 const short* __restrict__ Wf,
                                 short* __restrict__ Y, int nrows) {
  constexpr int NT = COLS / 16;
  const int wave = threadIdx.x >> 6;
  const int lane = threadIdx.x & 63;
  const int m = lane & 15;
  const int q = lane >> 4;
  const int rowA = bid * 64 + wave * 16 + m;
  const int row = min(rowA, nrows - 1);  // clamp; stores are guarded below

  short8 a[4];
  if constexpr (IN_BF16) {
    const short* xp = (const short*)Av + (size_t)row * 128 + q * 8;
#pragma unroll
    for (int c = 0; c < 4; c++) a[c] = *(const short8*)(xp + c * 32);
  } else {
    const float* xp = (const float*)Av + (size_t)row * 128 + q * 8;
#pragma unroll
    for (int c = 0; c < 4; c++) {
      float4 x0 = *(const float4*)(xp + c * 32);
      float4 x1 = *(const float4*)(xp + c * 32 + 4);
      short8 v;
      v[0] = f32_bf16(x0.x); v[1] = f32_bf16(x0.y);
      v[2] = f32_bf16(x0.z); v[3] = f32_bf16(x0.w);
      v[4] = f32_bf16(x1.x); v[5] = f32_bf16(x1.y);
      v[6] = f32_bf16(x1.z); v[7] = f32_bf16(x1.w);
      a[c] = v;
    }
  }

  const short8* wf8 = (const short8*)Wf;
  float4v acc[NT];
#pragma unroll
  for (int t = 0; t < NT; t++) acc[t] = (float4v){0.f, 0.f, 0.f, 0.f};
#pragma unroll
  for (int c = 0; c < 4; c++) {
#pragma unroll
    for (int t = 0; t < NT; t++) {
      acc[t] = __builtin_amdgcn_mfma_f32_16x16x32_bf16(
          a[c], wf8[(t * 4 + c) * 64 + lane], acc[t], 0, 0, 0);
    }
  }

  const int rbase = bid * 64 + wave * 16 + q * 4;
#pragma unroll
  for (int t = 0; t < NT; t++) {
#pragma unroll
    for (int r = 0; r < 4; r++) {
      int rr = rbase + r;
      if (rr < nrows)
        Y[((size_t)t * nrows + rr) * 16 + m] = f32_bf16(acc[t][r]);
    }
  }
}

// standalone gemm kernel (layer 2) — LDS-free, plane-major output
template <int COLS, bool IN_BF16>
__global__ __launch_bounds__(256) void gemm_mfma(
    const void* __restrict__ Av, const short* __restrict__ Wf,
    short* __restrict__ Y, int nrows) {
  gemm_role<COLS, IN_BF16>(blockIdx.x, Av, Wf, Y, nrows);
}

// ---------------------------------------------------------------------------
// Bin COUNT role: per-chunk LDS histogram of dst buckets, written to
// chunk_hist[b * NCHUNK + chunk] with plain stores. NO global atomics.
// ---------------------------------------------------------------------------
__device__ inline void bincount_role(int c, const int* __restrict__ dst,
                                     int* __restrict__ chunk_hist, int E,
                                     int NB, int NCHUNK, int* hist) {
  const int tid = threadIdx.x;
  const int base = c * CHUNK;
  const int end = min(E, base + CHUNK);
  for (int i = tid; i < NB; i += 256) hist[i] = 0;
  __syncthreads();
#pragma unroll 4
  for (int e = base + tid; e < end; e += 256)
    atomicAdd(&hist[dst[e] >> BSHIFT], 1);
  __syncthreads();
  for (int b = tid; b < NB; b += 256)
    chunk_hist[(size_t)b * NCHUNK + c] = hist[b];
}

// ---------------------------------------------------------------------------
// K1: fused gemm1 + bin-count. Bin blocks first. LDS 2 KB.
// ---------------------------------------------------------------------------
__global__ __launch_bounds__(256) void k1_gemm_bin(
    const float* __restrict__ x, const short* __restrict__ w1f,
    short* __restrict__ y1, int nrows, int nbin,
    const int* __restrict__ dst, int* __restrict__ chunk_hist,
    int E, int NB, int NCHUNK) {
  __shared__ int hist[512];
  if ((int)blockIdx.x < nbin) {
    bincount_role(blockIdx.x, dst, chunk_hist, E, NB, NCHUNK, hist);
  } else {
    gemm_role<128, false>(blockIdx.x - nbin, x, w1f, y1, nrows);
  }
}

// ---------------------------------------------------------------------------
// Per-bucket scan over chunks: one block per bucket, LDS scan of NCHUNK
// values -> within-bucket exclusive prefixes + bucket total.
// ---------------------------------------------------------------------------
__global__ __launch_bounds__(256) void chunk_scan_kernel(
    const int* __restrict__ chunk_hist, int* __restrict__ chunk_pref,
    int* __restrict__ bucket_cnt, int NCHUNK) {
  __shared__ int sh[256];
  const int b = blockIdx.x;
  const int t = threadIdx.x;
  int v = (t < NCHUNK) ? chunk_hist[(size_t)b * NCHUNK + t] : 0;
  sh[t] = v;
  __syncthreads();
  for (int off = 1; off < 256; off <<= 1) {
    int o = (t >= off) ? sh[t - off] : 0;
    __syncthreads();
    sh[t] += o;
    __syncthreads();
  }
  if (t < NCHUNK) chunk_pref[(size_t)b * NCHUNK + t] = sh[t] - v;
  if (t == 255) bucket_cnt[b] = sh[255];
}

// ---------------------------------------------------------------------------
// Cross-bucket exclusive scan (NB <= 512); also zeroes the agg work queues.
// ---------------------------------------------------------------------------
__global__ __launch_bounds__(512) void bucket_scan_kernel(
    const int* __restrict__ bucket_cnt, int* __restrict__ bucket_base,
    int* __restrict__ offsets, int* __restrict__ qcur,
    int NB, int N, int E) {
  __shared__ int sh[512];
  const int t = threadIdx.x;
  int v = (t < NB) ? bucket_cnt[t] : 0;
  sh[t] = v;
  __syncthreads();
  for (int off = 1; off < 512; off <<= 1) {
    int o = (t >= off) ? sh[t - off] : 0;
    __syncthreads();
    sh[t] += o;
    __syncthreads();
  }
  if (t < NB) bucket_base[t] = sh[t] - v;  // exclusive
  if (t == 0) offsets[N] = E;
  if (t < 16) qcur[t] = 0;
}

// ---------------------------------------------------------------------------
// Scatter: re-read chunk, place each edge at its exact precomputed slot.
// LDS atomics only; global ranges disjoint. bucket_arr is COMPACT (E).
// ---------------------------------------------------------------------------
__global__ __launch_bounds__(256) void scatter_kernel(
    const int* __restrict__ src, const int* __restrict__ dst,
    const int* __restrict__ chunk_pref, const int* __restrict__ bucket_base,
    int* __restrict__ bucket_arr, int E, int NB, int NCHUNK) {
  __shared__ int cur[512];
  const int c = blockIdx.x;
  const int tid = threadIdx.x;
  const int base = c * CHUNK;
  const int end = min(E, base + CHUNK);
  for (int b = tid; b < NB; b += 256)
    cur[b] = bucket_base[b] + chunk_pref[(size_t)b * NCHUNK + c];
  __syncthreads();
#pragma unroll 4
  for (int e = base + tid; e < end; e += 256) {
    int d = dst[e];
    int b = d >> BSHIFT;
    int pos = atomicAdd(&cur[b], 1);
    bucket_arr[pos] = (src[e] << BSHIFT) | (d & 255);
  }
}

// ---------------------------------------------------------------------------
// One block per bucket: LDS counting sort -> coalesced csr_src + offsets.
// ---------------------------------------------------------------------------
__global__ __launch_bounds__(256) void csr_build_kernel(
    const int* __restrict__ bucket_arr, const int* __restrict__ bucket_cnt,
    const int* __restrict__ bucket_base, int* __restrict__ offsets,
    int* __restrict__ csr_src, int N) {
  __shared__ int eds[BCAP];
  __shared__ int stage[BCAP];
  __shared__ int cnt256[256], pfx[256], cur[256];
  const int b = blockIdx.x;
  const int tid = threadIdx.x;
  const int cnt = bucket_cnt[b];
  const int gbase = bucket_base[b];
  const int node0 = b << BSHIFT;
  const int nnodes = min(256, N - node0);

  for (int i = tid; i < cnt; i += 256) eds[i] = bucket_arr[gbase + i];
  cnt256[tid] = 0;
  __syncthreads();
  for (int i = tid; i < cnt; i += 256) atomicAdd(&cnt256[eds[i] & 255], 1);
  __syncthreads();
  int v = cnt256[tid];
  pfx[tid] = v;
  __syncthreads();
  for (int off = 1; off < 256; off <<= 1) {
    int o = (tid >= off) ? pfx[tid - off] : 0;
    __syncthreads();
    pfx[tid] += o;
    __syncthreads();
  }
  int excl = pfx[tid] - v;
  cur[tid] = excl;
  if (tid < nnodes) offsets[node0 + tid] = gbase + excl;
  __syncthreads();
  for (int i = tid; i < cnt; i += 256) {
    int e = eds[i];
    int pos = atomicAdd(&cur[e & 255], 1);
    stage[pos] = e >> BSHIFT;
  }
  __syncthreads();
  for (int i = tid; i < cnt; i += 256) csr_src[gbase + i] = stage[i];
}

// ---------------------------------------------------------------------------
// agg1 sliced: 8 feature slices (plane-major y1), XCD-pinned via real
// XCC_ID + per-slice atomic work queues (stealing fallback keeps it correct
// even if the id is wrong). Per slice the gathered plane is 3.2 MB -> L2
// resident on its XCD. Wave: 16 edges x 4 lanes x 8 B; csr read nontemporal.
// ---------------------------------------------------------------------------
__global__ __launch_bounds__(256) void agg1_sliced_kernel(
    const short* __restrict__ Yp, const int* __restrict__ csr_src,
    const int* __restrict__ offsets, const float* __restrict__ bias,
    short* __restrict__ H, int N, int* __restrict__ qcur) {
  __shared__ int s_unit;
  const int nunits = (N + AGG_UNIT - 1) / AGG_UNIT;
  const int wave = threadIdx.x >> 6;
  const int lane = threadIdx.x & 63;
  const int grp = lane >> 2;   // 0..15: edge slot
  const int fl = lane & 3;     // feature quad within the slice
  const int xcc = get_xcc();
  for (int attempt = 0; attempt < 8; attempt++) {
    const int slice = (xcc + attempt) & 7;
    const short* Ys = Yp + (size_t)slice * N * 16 + fl * 4;
    const float4 bf = *(const float4*)&bias[slice * 16 + fl * 4];
    for (;;) {
      __syncthreads();
      if (threadIdx.x == 0) s_unit = atomicAdd(&qcur[slice], 1);
      __syncthreads();
      const int unit = s_unit;
      if (unit >= nunits) break;
      const int nbase = unit * AGG_UNIT + wave * (AGG_UNIT / 4);
      const int nend = min(nbase + AGG_UNIT / 4, N);
      for (int node = nbase; node < nend; node++) {
        const int start = offsets[node];
        const int end = offsets[node + 1];
        float a0 = 0.f, a1 = 0.f, a2 = 0.f, a3 = 0.f;
        for (int base = start; base < end; base += 64) {
          int gi = base + lane;
          int my = (gi < end) ? __builtin_nontemporal_load(csr_src + gi) : 0;
          int mcnt = min(64, end - base);
          for (int j = 0; j < mcnt; j += 16) {
            int idx = j + grp;
            int s = __shfl(my, min(idx, mcnt - 1));
            uint2v v = *(const uint2v*)(Ys + (size_t)s * 16);
            if (idx < mcnt) {
              a0 += bf16_lo(v.x); a1 += bf16_hi(v.x);
              a2 += bf16_lo(v.y); a3 += bf16_hi(v.y);
            }
          }
        }
        a0 += __shfl_xor(a0, 4); a0 += __shfl_xor(a0, 8);
        a0 += __shfl_xor(a0, 16); a0 += __shfl_xor(a0, 32);
        a1 += __shfl_xor(a1, 4); a1 += __shfl_xor(a1, 8);
        a1 += __shfl_xor(a1, 16); a1 += __shfl_xor(a1, 32);
        a2 += __shfl_xor(a2, 4); a2 += __shfl_xor(a2, 8);
        a2 += __shfl_xor(a2, 16); a2 += __shfl_xor(a2, 32);
        a3 += __shfl_xor(a3, 4); a3 += __shfl_xor(a3, 8);
        a3 += __shfl_xor(a3, 16); a3 += __shfl_xor(a3, 32);
        if (grp == 0) {
          float r0 = fmaxf(a0 + bf.x, 0.f);
          float r1 = fmaxf(a1 + bf.y, 0.f);
          float r2 = fmaxf(a2 + bf.z, 0.f);
          float r3 = fmaxf(a3 + bf.w, 0.f);
          uint2v o;
          o.x = (unsigned)(unsigned short)f32_bf16(r0) |
                ((unsigned)(unsigned short)f32_bf16(r1) << 16);
          o.y = (unsigned)(unsigned short)f32_bf16(r2) |
                ((unsigned)(unsigned short)f32_bf16(r3) << 16);
          *(uint2v*)&H[(size_t)node * 128 + slice * 16 + fl * 4] = o;
        }
      }
    }
  }
}

// ---------------------------------------------------------------------------
// agg2 sliced: 4 slices over plane-major y2 (each plane 3.2 MB; 2 XCDs per
// slice keep private copies). Output fp32 row-major [N][64].
// ---------------------------------------------------------------------------
__global__ __launch_bounds__(256) void agg2_sliced_kernel(
    const short* __restrict__ Yp, const int* __restrict__ csr_src,
    const int* __restrict__ offsets, const float* __restrict__ bias,
    float* __restrict__ out, int N, int* __restrict__ qcur) {
  __shared__ int s_unit;
  const int nunits = (N + AGG_UNIT - 1) / AGG_UNIT;
  const int wave = threadIdx.x >> 6;
  const int lane = threadIdx.x & 63;
  const int grp = lane >> 2;
  const int fl = lane & 3;
  const int xcc = get_xcc();
  for (int attempt = 0; attempt < 4; attempt++) {
    const int slice = (xcc + attempt) & 3;
    const short* Ys = Yp + (size_t)slice * N * 16 + fl * 4;
    const float4 bf = *(const float4*)&bias[slice * 16 + fl * 4];
    for (;;) {
      __syncthreads();
      if (threadIdx.x == 0) s_unit = atomicAdd(&qcur[slice], 1);
      __syncthreads();
      const int unit = s_unit;
      if (unit >= nunits) break;
      const int nbase = unit * AGG_UNIT + wave * (AGG_UNIT / 4);
      const int nend = min(nbase + AGG_UNIT / 4, N);
      for (int node = nbase; node < nend; node++) {
        const int start = offsets[node];
        const int end = offsets[node + 1];
        float a0 = 0.f, a1 = 0.f, a2 = 0.f, a3 = 0.f;
        for (int base = start; base < end; base += 64) {
          int gi = base + lane;
          int my = (gi < end) ? __builtin_nontemporal_load(csr_src + gi) : 0;
          int mcnt = min(64, end - base);
          for (int j = 0; j < mcnt; j += 16) {
            int idx = j + grp;
            int s = __shfl(my, min(idx, mcnt - 1));
            uint2v v = *(const uint2v*)(Ys + (size_t)s * 16);
            if (idx < mcnt) {
              a0 += bf16_lo(v.x); a1 += bf16_hi(v.x);
              a2 += bf16_lo(v.y); a3 += bf16_hi(v.y);
            }
          }
        }
        a0 += __shfl_xor(a0, 4); a0 += __shfl_xor(a0, 8);
        a0 += __shfl_xor(a0, 16); a0 += __shfl_xor(a0, 32);
        a1 += __shfl_xor(a1, 4); a1 += __shfl_xor(a1, 8);
        a1 += __shfl_xor(a1, 16); a1 += __shfl_xor(a1, 32);
        a2 += __shfl_xor(a2, 4); a2 += __shfl_xor(a2, 8);
        a2 += __shfl_xor(a2, 16); a2 += __shfl_xor(a2, 32);
        a3 += __shfl_xor(a3, 4); a3 += __shfl_xor(a3, 8);
        a3 += __shfl_xor(a3, 16); a3 += __shfl_xor(a3, 32);
        if (grp == 0) {
          float4 o;
          o.x = a0 + bf.x; o.y = a1 + bf.y;
          o.z = a2 + bf.z; o.w = a3 + bf.w;
          *(float4*)&out[(size_t)node * 64 + slice * 16 + fl * 4] = o;
        }
      }
    }
  }
}

extern "C" void kernel_launch(void* const* d_in, const int* in_sizes, int n_in,
                              void* d_out, int out_size, void* d_ws, size_t ws_size,
                              hipStream_t stream) {
  const float* x  = (const float*)d_in[0];
  const int* src  = (const int*)d_in[1];
  const int* dst  = (const int*)d_in[2];
  const float* W1 = (const float*)d_in[3];
  const float* b1 = (const float*)d_in[4];
  const float* W2 = (const float*)d_in[5];
  const float* b2 = (const float*)d_in[6];
  float* out = (float*)d_out;

  const int N = in_sizes[0] / NFEAT;        // 100000
  const int E = in_sizes[1];                // 1600000
  const int NB = (N + 255) >> BSHIFT;       // 391 buckets
  const int NCHUNK = (E + CHUNK - 1) / CHUNK;  // 196 chunks (<= 256)

  // workspace layout
  short* y1  = (short*)d_ws;                       // N*128 bf16 (plane-major)
  short* h   = y1 + (size_t)N * 128;               // N*128 bf16 (row-major)
  short* y2  = h + (size_t)N * 128;                // N*64 bf16 (plane-major)
  short* w1f = y2 + (size_t)N * 64;                // 128*128 bf16
  short* w2f = w1f + 128 * 128;                    // 128*64 bf16
  int* bucket_cnt  = (int*)(((uintptr_t)(w2f + 128 * 64) + 15) & ~(uintptr_t)15);
  int* bucket_base = bucket_cnt + 512;             // 512
  int* offsets     = bucket_base + 512;            // N+1
  int* csr_src     = offsets + N + 1;              // E
  int* bucket_arr  = csr_src + E;                  // E (compact)
  int* chunk_hist  = bucket_arr + E;               // NB*NCHUNK
  int* chunk_pref  = chunk_hist + (size_t)NB * NCHUNK;  // NB*NCHUNK
  int* qcur        = chunk_pref + (size_t)NB * NCHUNK;  // 16 work-queue heads

  const int gemm_blocks = (N + 63) / 64;
  const int nunits = (N + AGG_UNIT - 1) / AGG_UNIT;  // 782

  // ---- weight repack (must finish before K1 reads w1f) ----
  repack_w_kernel<<<2, 256, 0, stream>>>(W1, w1f, W2, w2f);

  // ---- K1: gemm1 fused with bin-count (no global atomics) ----
  k1_gemm_bin<<<gemm_blocks + NCHUNK, 256, 0, stream>>>(
      x, w1f, y1, N, NCHUNK, dst, chunk_hist, E, NB, NCHUNK);

  // ---- per-bucket scan over chunks (391 parallel blocks) ----
  chunk_scan_kernel<<<NB, 256, 0, stream>>>(chunk_hist, chunk_pref,
                                            bucket_cnt, NCHUNK);

  // ---- cross-bucket scan + queue reset (tiny) ----
  bucket_scan_kernel<<<1, 512, 0, stream>>>(bucket_cnt, bucket_base, offsets,
                                            qcur, NB, N, E);

  // ---- scatter to compact bucket_arr (no global atomics) ----
  scatter_kernel<<<NCHUNK, 256, 0, stream>>>(src, dst, chunk_pref, bucket_base,
                                             bucket_arr, E, NB, NCHUNK);

  // ---- CSR finalize ----
  csr_build_kernel<<<NB, 256, 0, stream>>>(bucket_arr, bucket_cnt, bucket_base,
                                           offsets, csr_src, N);

  // ---- layer-1 aggregation: 8 XCD-pinned slices ----
  agg1_sliced_kernel<<<nunits * 8, 256, 0, stream>>>(y1, csr_src, offsets, b1,
                                                     h, N, qcur);

  // ---- layer-2 gemm ----
  gemm_mfma<64, true><<<gemm_blocks, 256, 0, stream>>>(h, w2f, y2, N);

  // ---- layer-2 aggregation: 4 XCD-pinned slices ----
  agg2_sliced_kernel<<<nunits * 4, 256, 0, stream>>>(y2, csr_src, offsets, b2,
                                                     out, N, qcur + 8);
}

// Round 10
// 256.635 us; speedup vs baseline: 4.3510x; 4.3510x over previous
//
#include <hip/hip_runtime.h>
#include <hip/hip_bf16.h>

#define NFEAT 128
#define BCAP 8192     // max edges per 256-node bucket (csr_build LDS capacity)
#define BSHIFT 8      // 256 nodes per bucket
#define CHUNK 8192    // bin-pass chunk size (edges per count/scatter block)

typedef __attribute__((ext_vector_type(8))) short short8;
typedef __attribute__((ext_vector_type(4))) float float4v;

__device__ inline short f32_bf16(float f) {
  unsigned u = __builtin_bit_cast(unsigned, f);
  unsigned r = (u + 0x7fffu + ((u >> 16) & 1u)) >> 16;
  return (short)r;
}
__device__ inline float bf16_f32(unsigned short s) {
  return __builtin_bit_cast(float, (unsigned)s << 16);
}

// ---------------------------------------------------------------------------
// Repack W (fp32, KxCOLS row-major) into B-fragment order for
// mfma_f32_16x16x32_bf16.
// ---------------------------------------------------------------------------
__device__ inline void repack_one(const float* __restrict__ W,
                                  short* __restrict__ Wf, int COLS) {
  int nfrag = (COLS / 16) * 4 * 64;
  for (int f = threadIdx.x; f < nfrag; f += 256) {
    int lane = f & 63, c = (f >> 6) & 3, t = f >> 8;
    int k0 = c * 32 + (lane >> 4) * 8;
    int n = t * 16 + (lane & 15);
    short8 v;
#pragma unroll
    for (int j = 0; j < 8; j++) v[j] = f32_bf16(W[(size_t)(k0 + j) * COLS + n]);
    *(short8*)&Wf[(size_t)f * 8] = v;
  }
}
__global__ __launch_bounds__(256) void repack_w_kernel(
    const float* __restrict__ W1, short* __restrict__ W1f,
    const float* __restrict__ W2, short* __restrict__ W2f) {
  if (blockIdx.x == 0) repack_one(W1, W1f, 128);
  else repack_one(W2, W2f, 64);
}

// ---------------------------------------------------------------------------
// GEMM device role: Y_bf16[nrows x COLS] = A[nrows x 128] @ W[128 x COLS]
// B-fragments read directly from global (w*f is 32/16 KB, L2/L1-resident).
// ---------------------------------------------------------------------------
template <int COLS, bool IN_BF16>
__device__ inline void gemm_role(int bid, const void* __restrict__ Av,
                                 const short* __restrict__ Wf,
                                 short* __restrict__ Y, int nrows) {
  constexpr int NT = COLS / 16;
  const int wave = threadIdx.x >> 6;
  const int lane = threadIdx.x & 63;
  const int m = lane & 15;
  const int q = lane >> 4;
  const int rowA = bid * 64 + wave * 16 + m;
  const int row = min(rowA, nrows - 1);  // clamp; stores are guarded below

  short8 a[4];
  if constexpr (IN_BF16) {
    const short* xp = (const short*)Av + (size_t)row * 128 + q * 8;
#pragma unroll
    for (int c = 0; c < 4; c++) a[c] = *(const short8*)(xp + c * 32);
  } else {
    const float* xp = (const float*)Av + (size_t)row * 128 + q * 8;
#pragma unroll
    for (int c = 0; c < 4; c++) {
      float4 x0 = *(const float4*)(xp + c * 32);
      float4 x1 = *(const float4*)(xp + c * 32 + 4);
      short8 v;
      v[0] = f32_bf16(x0.x); v[1] = f32_bf16(x0.y);
      v[2] = f32_bf16(x0.z); v[3] = f32_bf16(x0.w);
      v[4] = f32_bf16(x1.x); v[5] = f32_bf16(x1.y);
      v[6] = f32_bf16(x1.z); v[7] = f32_bf16(x1.w);
      a[c] = v;
    }
  }

  const short8* wf8 = (const short8*)Wf;
  float4v acc[NT];
#pragma unroll
  for (int t = 0; t < NT; t++) acc[t] = (float4v){0.f, 0.f, 0.f, 0.f};
#pragma unroll
  for (int c = 0; c < 4; c++) {
#pragma unroll
    for (int t = 0; t < NT; t++) {
      acc[t] = __builtin_amdgcn_mfma_f32_16x16x32_bf16(
          a[c], wf8[(t * 4 + c) * 64 + lane], acc[t], 0, 0, 0);
    }
  }

  const int rbase = bid * 64 + wave * 16 + q * 4;
#pragma unroll
  for (int t = 0; t < NT; t++) {
#pragma unroll
    for (int r = 0; r < 4; r++) {
      int rr = rbase + r;
      if (rr < nrows) Y[(size_t)rr * COLS + t * 16 + m] = f32_bf16(acc[t][r]);
    }
  }
}

// ---------------------------------------------------------------------------
// Bin COUNT role: per-chunk LDS histogram of dst buckets, written to
// chunk_hist[b * NCHUNK + chunk] with plain stores. NO global atomics.
// ---------------------------------------------------------------------------
__device__ inline void bincount_role(int c, const int* __restrict__ dst,
                                     int* __restrict__ chunk_hist, int E,
                                     int NB, int NCHUNK, int* hist) {
  const int tid = threadIdx.x;
  const int base = c * CHUNK;
  const int end = min(E, base + CHUNK);
  for (int i = tid; i < NB; i += 256) hist[i] = 0;
  __syncthreads();
#pragma unroll 4
  for (int e = base + tid; e < end; e += 256)
    atomicAdd(&hist[dst[e] >> BSHIFT], 1);
  __syncthreads();
  for (int b = tid; b < NB; b += 256)
    chunk_hist[(size_t)b * NCHUNK + c] = hist[b];
}

// ---------------------------------------------------------------------------
// K1: fused gemm1 + bin-count. Bin blocks first. LDS 2 KB.
// ---------------------------------------------------------------------------
__global__ __launch_bounds__(256) void k1_gemm_bin(
    const float* __restrict__ x, const short* __restrict__ w1f,
    short* __restrict__ y1, int nrows, int nbin,
    const int* __restrict__ dst, int* __restrict__ chunk_hist,
    int E, int NB, int NCHUNK) {
  __shared__ int hist[512];
  if ((int)blockIdx.x < nbin) {
    bincount_role(blockIdx.x, dst, chunk_hist, E, NB, NCHUNK, hist);
  } else {
    gemm_role<128, false>(blockIdx.x - nbin, x, w1f, y1, nrows);
  }
}

// ---------------------------------------------------------------------------
// Per-bucket scan over chunks: one block per bucket, LDS scan of NCHUNK
// values -> within-bucket exclusive prefixes + bucket total.
// ---------------------------------------------------------------------------
__global__ __launch_bounds__(256) void chunk_scan_kernel(
    const int* __restrict__ chunk_hist, int* __restrict__ chunk_pref,
    int* __restrict__ bucket_cnt, int NCHUNK) {
  __shared__ int sh[256];
  const int b = blockIdx.x;
  const int t = threadIdx.x;
  int v = (t < NCHUNK) ? chunk_hist[(size_t)b * NCHUNK + t] : 0;
  sh[t] = v;
  __syncthreads();
  for (int off = 1; off < 256; off <<= 1) {
    int o = (t >= off) ? sh[t - off] : 0;
    __syncthreads();
    sh[t] += o;
    __syncthreads();
  }
  if (t < NCHUNK) chunk_pref[(size_t)b * NCHUNK + t] = sh[t] - v;
  if (t == 255) bucket_cnt[b] = sh[255];
}

// ---------------------------------------------------------------------------
// Cross-bucket exclusive scan (NB <= 512), one small block; offsets[N]=E.
// ---------------------------------------------------------------------------
__global__ __launch_bounds__(512) void bucket_scan_kernel(
    const int* __restrict__ bucket_cnt, int* __restrict__ bucket_base,
    int* __restrict__ offsets, int NB, int N, int E) {
  __shared__ int sh[512];
  const int t = threadIdx.x;
  int v = (t < NB) ? bucket_cnt[t] : 0;
  sh[t] = v;
  __syncthreads();
  for (int off = 1; off < 512; off <<= 1) {
    int o = (t >= off) ? sh[t - off] : 0;
    __syncthreads();
    sh[t] += o;
    __syncthreads();
  }
  if (t < NB) bucket_base[t] = sh[t] - v;  // exclusive
  if (t == 0) offsets[N] = E;
}

// ---------------------------------------------------------------------------
// Scatter: re-read chunk, place each edge at its exact precomputed slot.
// LDS atomics only; global ranges disjoint. bucket_arr is COMPACT (E).
// ---------------------------------------------------------------------------
__global__ __launch_bounds__(256) void scatter_kernel(
    const int* __restrict__ src, const int* __restrict__ dst,
    const int* __restrict__ chunk_pref, const int* __restrict__ bucket_base,
    int* __restrict__ bucket_arr, int E, int NB, int NCHUNK) {
  __shared__ int cur[512];
  const int c = blockIdx.x;
  const int tid = threadIdx.x;
  const int base = c * CHUNK;
  const int end = min(E, base + CHUNK);
  for (int b = tid; b < NB; b += 256)
    cur[b] = bucket_base[b] + chunk_pref[(size_t)b * NCHUNK + c];
  __syncthreads();
#pragma unroll 4
  for (int e = base + tid; e < end; e += 256) {
    int d = dst[e];
    int b = d >> BSHIFT;
    int pos = atomicAdd(&cur[b], 1);
    bucket_arr[pos] = (src[e] << BSHIFT) | (d & 255);
  }
}

// ---------------------------------------------------------------------------
// One block per bucket: LDS counting sort -> coalesced csr_src + offsets.
// ---------------------------------------------------------------------------
__global__ __launch_bounds__(256) void csr_build_kernel(
    const int* __restrict__ bucket_arr, const int* __restrict__ bucket_cnt,
    const int* __restrict__ bucket_base, int* __restrict__ offsets,
    int* __restrict__ csr_src, int N) {
  __shared__ int eds[BCAP];
  __shared__ int stage[BCAP];
  __shared__ int cnt256[256], pfx[256], cur[256];
  const int b = blockIdx.x;
  const int tid = threadIdx.x;
  const int cnt = bucket_cnt[b];
  const int gbase = bucket_base[b];
  const int node0 = b << BSHIFT;
  const int nnodes = min(256, N - node0);

  for (int i = tid; i < cnt; i += 256) eds[i] = bucket_arr[gbase + i];
  cnt256[tid] = 0;
  __syncthreads();
  for (int i = tid; i < cnt; i += 256) atomicAdd(&cnt256[eds[i] & 255], 1);
  __syncthreads();
  int v = cnt256[tid];
  pfx[tid] = v;
  __syncthreads();
  for (int off = 1; off < 256; off <<= 1) {
    int o = (tid >= off) ? pfx[tid - off] : 0;
    __syncthreads();
    pfx[tid] += o;
    __syncthreads();
  }
  int excl = pfx[tid] - v;
  cur[tid] = excl;
  if (tid < nnodes) offsets[node0 + tid] = gbase + excl;
  __syncthreads();
  for (int i = tid; i < cnt; i += 256) {
    int e = eds[i];
    int pos = atomicAdd(&cur[e & 255], 1);
    stage[pos] = e >> BSHIFT;
  }
  __syncthreads();
  for (int i = tid; i < cnt; i += 256) csr_src[gbase + i] = stage[i];
}

// ---------------------------------------------------------------------------
// FUSED agg1 + gemm2: block handles 64 nodes. Each wave aggregates its own
// 16 rows (proven gather loop), applies bias+ReLU, parks bf16 rows in LDS
// (XOR-swizzled: key ((row&7)<<3) on the short index; bit 0 untouched so the
// 2-feature pair stays a single aligned 4 B store), then runs the 64x64x128
// MFMA from LDS. h never touches global memory.
// ---------------------------------------------------------------------------
__global__ __launch_bounds__(256) void agg1_gemm2_kernel(
    const short* __restrict__ Y, const int* __restrict__ csr_src,
    const int* __restrict__ offsets, const float* __restrict__ b1,
    const short* __restrict__ w2f, short* __restrict__ y2, int N) {
  __shared__ __align__(16) short hls[64 * 128];  // 16 KB, swizzled
  const int wave = threadIdx.x >> 6;
  const int lane = threadIdx.x & 63;
  const int node0 = blockIdx.x * 64 + wave * 16;
  const float bias0 = b1[2 * lane], bias1 = b1[2 * lane + 1];

  for (int i = 0; i < 16; i++) {
    const int node = node0 + i;
    float a0 = bias0, a1 = bias1;
    if (node < N) {
      const int start = offsets[node];
      const int end = offsets[node + 1];
      for (int base = start; base < end; base += 64) {
        int my = (base + lane < end) ? csr_src[base + lane] : 0;
        int mcnt = min(64, end - base);
        int j = 0;
        for (; j + 8 <= mcnt; j += 8) {
          unsigned v[8];
#pragma unroll
          for (int k = 0; k < 8; k++) {
            int s = __shfl(my, j + k);
            v[k] = *(const unsigned*)&Y[(size_t)s * 128 + 2 * lane];
          }
#pragma unroll
          for (int k = 0; k < 8; k++) {
            a0 += __builtin_bit_cast(float, v[k] << 16);
            a1 += __builtin_bit_cast(float, v[k] & 0xffff0000u);
          }
        }
        for (; j + 4 <= mcnt; j += 4) {
          unsigned v[4];
#pragma unroll
          for (int k = 0; k < 4; k++) {
            int s = __shfl(my, j + k);
            v[k] = *(const unsigned*)&Y[(size_t)s * 128 + 2 * lane];
          }
#pragma unroll
          for (int k = 0; k < 4; k++) {
            a0 += __builtin_bit_cast(float, v[k] << 16);
            a1 += __builtin_bit_cast(float, v[k] & 0xffff0000u);
          }
        }
        for (; j < mcnt; j++) {
          int s = __shfl(my, j);
          unsigned v = *(const unsigned*)&Y[(size_t)s * 128 + 2 * lane];
          a0 += __builtin_bit_cast(float, v << 16);
          a1 += __builtin_bit_cast(float, v & 0xffff0000u);
        }
      }
    }
    a0 = fmaxf(a0, 0.f);
    a1 = fmaxf(a1, 0.f);
    unsigned outv = (unsigned)(unsigned short)f32_bf16(a0) |
                    ((unsigned)(unsigned short)f32_bf16(a1) << 16);
    const int so = (2 * lane) ^ ((i & 7) << 3);  // even -> 4B-aligned
    *(unsigned*)&hls[(wave * 16 + i) * 128 + so] = outv;
  }
  __syncthreads();

  // ---- gemm2 from LDS: Y2[64 x 64] = H[64 x 128] @ W2 ----
  const int m = lane & 15;
  const int q = lane >> 4;
  short8 a[4];
#pragma unroll
  for (int c = 0; c < 4; c++)
    a[c] = *(const short8*)&hls[(wave * 16 + m) * 128 +
                                ((c * 32 + q * 8) ^ ((m & 7) << 3))];

  const short8* wf8 = (const short8*)w2f;
  float4v acc[4];
#pragma unroll
  for (int t = 0; t < 4; t++) acc[t] = (float4v){0.f, 0.f, 0.f, 0.f};
#pragma unroll
  for (int c = 0; c < 4; c++) {
#pragma unroll
    for (int t = 0; t < 4; t++) {
      acc[t] = __builtin_amdgcn_mfma_f32_16x16x32_bf16(
          a[c], wf8[(t * 4 + c) * 64 + lane], acc[t], 0, 0, 0);
    }
  }

  const int rbase = blockIdx.x * 64 + wave * 16 + q * 4;
#pragma unroll
  for (int t = 0; t < 4; t++) {
#pragma unroll
    for (int r = 0; r < 4; r++) {
      int rr = rbase + r;
      if (rr < N) y2[(size_t)rr * 64 + t * 16 + m] = f32_bf16(acc[t][r]);
    }
  }
}

// ---------------------------------------------------------------------------
// agg2 (proven version): one wave per node, fp32 accumulate, 8-way unrolled.
// ---------------------------------------------------------------------------
__global__ __launch_bounds__(256) void agg2_kernel(
    const short* __restrict__ Y, const int* __restrict__ csr_src,
    const int* __restrict__ offsets, const float* __restrict__ bias,
    float* __restrict__ out, int N) {
  const int node = (blockIdx.x * 256 + threadIdx.x) >> 6;
  const int lane = threadIdx.x & 63;
  if (node >= N) return;
  const int start = offsets[node];
  const int end = offsets[node + 1];
  float acc = bias[lane];
  for (int base = start; base < end; base += 64) {
    int my = (base + lane < end) ? csr_src[base + lane] : 0;
    int mcnt = min(64, end - base);
    int j = 0;
    for (; j + 8 <= mcnt; j += 8) {
      unsigned short w[8];
#pragma unroll
      for (int k = 0; k < 8; k++) {
        int s = __shfl(my, j + k);
        w[k] = *(const unsigned short*)&Y[(size_t)s * 64 + lane];
      }
#pragma unroll
      for (int k = 0; k < 8; k++) acc += bf16_f32(w[k]);
    }
    for (; j + 4 <= mcnt; j += 4) {
      unsigned short w[4];
#pragma unroll
      for (int k = 0; k < 4; k++) {
        int s = __shfl(my, j + k);
        w[k] = *(const unsigned short*)&Y[(size_t)s * 64 + lane];
      }
#pragma unroll
      for (int k = 0; k < 4; k++) acc += bf16_f32(w[k]);
    }
    for (; j < mcnt; j++) {
      int s = __shfl(my, j);
      acc += bf16_f32(*(const unsigned short*)&Y[(size_t)s * 64 + lane]);
    }
  }
  out[(size_t)node * 64 + lane] = acc;
}

extern "C" void kernel_launch(void* const* d_in, const int* in_sizes, int n_in,
                              void* d_out, int out_size, void* d_ws, size_t ws_size,
                              hipStream_t stream) {
  const float* x  = (const float*)d_in[0];
  const int* src  = (const int*)d_in[1];
  const int* dst  = (const int*)d_in[2];
  const float* W1 = (const float*)d_in[3];
  const float* b1 = (const float*)d_in[4];
  const float* W2 = (const float*)d_in[5];
  const float* b2 = (const float*)d_in[6];
  float* out = (float*)d_out;

  const int N = in_sizes[0] / NFEAT;        // 100000
  const int E = in_sizes[1];                // 1600000
  const int NB = (N + 255) >> BSHIFT;       // 391 buckets
  const int NCHUNK = (E + CHUNK - 1) / CHUNK;  // 196 chunks (<= 256)

  // workspace layout (h removed — lives only in the fused kernel's LDS)
  short* y1  = (short*)d_ws;                       // N*128 bf16
  short* y2  = y1 + (size_t)N * 128;               // N*64 bf16
  short* w1f = y2 + (size_t)N * 64;                // 128*128 bf16
  short* w2f = w1f + 128 * 128;                    // 128*64 bf16
  int* bucket_cnt  = (int*)(((uintptr_t)(w2f + 128 * 64) + 15) & ~(uintptr_t)15);
  int* bucket_base = bucket_cnt + 512;             // 512
  int* offsets     = bucket_base + 512;            // N+1
  int* csr_src     = offsets + N + 1;              // E
  int* bucket_arr  = csr_src + E;                  // E (compact)
  int* chunk_hist  = bucket_arr + E;               // NB*NCHUNK
  int* chunk_pref  = chunk_hist + (size_t)NB * NCHUNK;  // NB*NCHUNK

  const int gemm_blocks = (N + 63) / 64;
  const int agg_blocks = (N * 64 + 255) / 256;

  // ---- weight repack (must finish before K1 reads w1f) ----
  repack_w_kernel<<<2, 256, 0, stream>>>(W1, w1f, W2, w2f);

  // ---- K1: gemm1 fused with bin-count (no global atomics) ----
  k1_gemm_bin<<<gemm_blocks + NCHUNK, 256, 0, stream>>>(
      x, w1f, y1, N, NCHUNK, dst, chunk_hist, E, NB, NCHUNK);

  // ---- per-bucket scan over chunks (391 parallel blocks) ----
  chunk_scan_kernel<<<NB, 256, 0, stream>>>(chunk_hist, chunk_pref,
                                            bucket_cnt, NCHUNK);

  // ---- cross-bucket scan (tiny) ----
  bucket_scan_kernel<<<1, 512, 0, stream>>>(bucket_cnt, bucket_base, offsets,
                                            NB, N, E);

  // ---- scatter to compact bucket_arr (no global atomics) ----
  scatter_kernel<<<NCHUNK, 256, 0, stream>>>(src, dst, chunk_pref, bucket_base,
                                             bucket_arr, E, NB, NCHUNK);

  // ---- CSR finalize ----
  csr_build_kernel<<<NB, 256, 0, stream>>>(bucket_arr, bucket_cnt, bucket_base,
                                           offsets, csr_src, N);

  // ---- fused layer-1 aggregation + layer-2 gemm ----
  agg1_gemm2_kernel<<<gemm_blocks, 256, 0, stream>>>(y1, csr_src, offsets, b1,
                                                     w2f, y2, N);

  // ---- layer-2 aggregation ----
  agg2_kernel<<<agg_blocks, 256, 0, stream>>>(y2, csr_src, offsets, b2, out, N);
}